// Round 5
// baseline (2382.169 us; speedup 1.0000x reference)
//
#include <hip/hip_runtime.h>

#define N_PTS   16384
#define K_CODES 8192
#define C_DIM   256
#define HW      1024   // 32*32

#define QOUT_SZ  (N_PTS * C_DIM)          // 4194304
#define LOSS_OFF QOUT_SZ
#define PERP_OFF (QOUT_SZ + 1)
#define IDX_OFF  (QOUT_SZ + 2)

// workspace byte offsets
#define WS_E2     0u          // 8192 f32   (32 KB)
#define WS_BESTV  32768u      // 2*16384 f32 (128 KB)
#define WS_BESTV2 163840u     // 2*16384 f32 (128 KB)
#define WS_BESTK  294912u     // 2*16384 i32 (128 KB)
#define WS_KFINAL 425984u     // 16384 i32  (64 KB)
#define WS_COUNTS 491520u     // 8192 i32   (32 KB)
#define WS_SUMSQ  524288u     // 1 f32
#define WS_RCOUNT 524292u     // 1 i32
#define WS_RLIST  524296u     // 16384 i32  (64 KB)
#define WS_EMBT   1048576u    // 256*8192 f32 (8 MB)

// ---------------- kernel 1: ||e_k||^2 ----------------
__global__ void e2_kernel(const float* __restrict__ emb, float* __restrict__ e2) {
    int row  = blockIdx.x * 4 + (threadIdx.x >> 6);
    int lane = threadIdx.x & 63;
    float4 v = *reinterpret_cast<const float4*>(emb + row * C_DIM + lane * 4);
    float s = v.x * v.x + v.y * v.y + v.z * v.z + v.w * v.w;
    #pragma unroll
    for (int off = 32; off > 0; off >>= 1) s += __shfl_down(s, off);
    if (lane == 0) e2[row] = s;
}

// ---------------- kernel 2: embT[c][k] = emb[k][c] ----------------
__global__ void transpose_kernel(const float* __restrict__ emb, float* __restrict__ embT) {
    __shared__ float tile[64][65];
    int k0 = blockIdx.x * 64;
    int c0 = blockIdx.y * 64;
    int cc  = threadIdx.x & 63;
    int kk0 = threadIdx.x >> 6;
    #pragma unroll
    for (int i = 0; i < 16; ++i) {
        int kk = kk0 * 16 + i;
        tile[kk][cc] = emb[(k0 + kk) * C_DIM + c0 + cc];
    }
    __syncthreads();
    int kk  = threadIdx.x & 63;
    int cc0 = threadIdx.x >> 6;
    #pragma unroll
    for (int i = 0; i < 16; ++i) {
        int cc2 = cc0 * 16 + i;
        embT[(c0 + cc2) * K_CODES + k0 + kk] = tile[kk][cc2];
    }
}

// ---------------- kernel 3: f32 argmin over K (split in 2 halves) ----------------
// block = 256 threads (16 tp x 16 tk); per block: 64 points x 4096 codes
// tracks best AND second-best per point (for near-tie refinement)
__global__ __launch_bounds__(256, 2) void argmin_kernel(
    const float* __restrict__ in, const float* __restrict__ embT,
    const float* __restrict__ e2,
    float* __restrict__ bestv_out, float* __restrict__ bestv2_out,
    int* __restrict__ bestk_out) {
    __shared__ float xsT[C_DIM * 64];  // [c][p]  64 KB (reused as reduce scratch)
    __shared__ float es[32 * 64];      // [c][k]   8 KB

    const int ntile = blockIdx.x;         // 0..255
    const int khalf = blockIdx.y;         // 0..1
    const int n0 = ntile * 64;
    const int b  = n0 >> 10;
    const int hw0 = n0 & 1023;
    const int t = threadIdx.x;

    // stage x tile: xsT[c][p], coalesced global reads (lane = p)
    {
        int p  = t & 63;
        int c0 = t >> 6;   // 0..3
        const float* src = in + (size_t)b * (C_DIM * HW) + hw0 + p;
        #pragma unroll 4
        for (int i = 0; i < 64; ++i) {
            int c = c0 * 64 + i;
            xsT[c * 64 + p] = src[c * HW];
        }
    }

    const int tp = t & 15;
    const int tk = t >> 4;

    float best[4]  = {1e30f, 1e30f, 1e30f, 1e30f};
    float best2[4] = {1e30f, 1e30f, 1e30f, 1e30f};
    int   bestk[4] = {0, 0, 0, 0};

    const int kbase0 = khalf * (K_CODES / 2);

    for (int kt = 0; kt < (K_CODES / 2) / 64; ++kt) {
        const int kbase = kbase0 + kt * 64;
        float acc[4][4] = {};
        for (int cb = 0; cb < 8; ++cb) {
            __syncthreads();   // protects xsT (first iter) and es reuse
            {
                int col4 = (t & 15) * 4;
                int r0   = (t >> 4) * 2;
                #pragma unroll
                for (int ii = 0; ii < 2; ++ii) {
                    int r = r0 + ii;
                    *reinterpret_cast<float4*>(&es[r * 64 + col4]) =
                        *reinterpret_cast<const float4*>(
                            &embT[(size_t)(cb * 32 + r) * K_CODES + kbase + col4]);
                }
            }
            __syncthreads();
            const float* xb = &xsT[cb * 32 * 64 + tp * 4];
            const float* eb = &es[tk * 4];
            #pragma unroll 4
            for (int c = 0; c < 32; ++c) {
                float4 xv = *reinterpret_cast<const float4*>(xb + c * 64);
                float4 ev = *reinterpret_cast<const float4*>(eb + c * 64);
                acc[0][0] += xv.x * ev.x; acc[0][1] += xv.x * ev.y;
                acc[0][2] += xv.x * ev.z; acc[0][3] += xv.x * ev.w;
                acc[1][0] += xv.y * ev.x; acc[1][1] += xv.y * ev.y;
                acc[1][2] += xv.y * ev.z; acc[1][3] += xv.y * ev.w;
                acc[2][0] += xv.z * ev.x; acc[2][1] += xv.z * ev.y;
                acc[2][2] += xv.z * ev.z; acc[2][3] += xv.z * ev.w;
                acc[3][0] += xv.w * ev.x; acc[3][1] += xv.w * ev.y;
                acc[3][2] += xv.w * ev.z; acc[3][3] += xv.w * ev.w;
            }
        }
        // epilogue: k ascending within thread -> strict < keeps first occurrence
        #pragma unroll
        for (int j = 0; j < 4; ++j) {
            int k = kbase + tk * 4 + j;
            float ek = e2[k];
            #pragma unroll
            for (int i = 0; i < 4; ++i) {
                float d = ek - 2.0f * acc[i][j];
                if (d < best[i]) { best2[i] = best[i]; best[i] = d; bestk[i] = k; }
                else if (d < best2[i]) { best2[i] = d; }
            }
        }
    }

    // cross-tk reduction via LDS (reuse xsT: 3 arrays of [64][16])
    __syncthreads();
    float* bv  = xsT;
    float* bv2 = xsT + 1024;
    int*   bk  = reinterpret_cast<int*>(xsT + 2048);
    #pragma unroll
    for (int i = 0; i < 4; ++i) {
        int r = (tp * 4 + i) * 16 + tk;
        bv[r] = best[i]; bv2[r] = best2[i]; bk[r] = bestk[i];
    }
    __syncthreads();
    if (t < 64) {
        int base = t * 16;
        float v = bv[base], v2 = bv2[base];
        int   k = bk[base];
        #pragma unroll
        for (int j = 1; j < 16; ++j) {
            float nv = bv[base + j], nv2 = bv2[base + j];
            int   nk = bk[base + j];
            if (nv < v || (nv == v && nk < k)) {
                v2 = fminf(v, nv2); v = nv; k = nk;
            } else {
                v2 = fminf(v2, nv);
            }
        }
        bestv_out [khalf * N_PTS + n0 + t] = v;
        bestv2_out[khalf * N_PTS + n0 + t] = v2;
        bestk_out [khalf * N_PTS + n0 + t] = k;
    }
}

// ---------------- kernel 4: merge halves, flag near-ties ----------------
__global__ void merge_kernel(const float* __restrict__ bestv,
                             const float* __restrict__ bestv2,
                             const int* __restrict__ bestk,
                             int* __restrict__ kfinal,
                             int* __restrict__ rlist, int* __restrict__ rcount) {
    int n = blockIdx.x * 256 + threadIdx.x;
    float va = bestv[n],  vb = bestv[N_PTS + n];
    float v2a = bestv2[n], v2b = bestv2[N_PTS + n];
    int   ka = bestk[n],  kb = bestk[N_PTS + n];
    float bst, snd; int k;
    if (vb < va) { bst = vb; k = kb; snd = fminf(va, v2b); }
    else         { bst = va; k = ka; snd = fminf(v2a, vb); }   // tie -> half 0 (smaller k)
    kfinal[n] = k;
    if (snd - bst < 1e-3f) {
        int p = atomicAdd(rcount, 1);
        rlist[p] = n;
    }
}

// ---------------- kernel 5: numpy-f32-EMULATING refine for flagged points ----------------
// Reference computes d = f32( f32(x2 + e2[k]) - f32(2*dot_f32) ) and argmin
// takes the FIRST minimum. We emulate: dot in f64 (proxy for BLAS's f32
// accum, err ~2e-6), cast to f32, then identical f32 rounding sequence.
// NOTE: 2.0f*dotf is exact (power-of-2), so fmaf contraction cannot change it.
__global__ void refine_kernel(const float* __restrict__ in, const float* __restrict__ emb,
                              const float* __restrict__ e2,
                              const int* __restrict__ rlist, const int* __restrict__ rcount,
                              int* __restrict__ kfinal) {
    __shared__ float xs[C_DIM];
    __shared__ float x2sh;
    __shared__ float bvals[4];
    __shared__ int   bks[4];
    const int t = threadIdx.x;
    const int wid = t >> 6, lane = t & 63;
    const int njobs = *rcount;

    for (int job = blockIdx.x; job < njobs; job += gridDim.x) {
        const int n = rlist[job];
        const int b = n >> 10, hw = n & 1023;
        __syncthreads();   // protect xs/x2sh/bvals reuse across jobs
        xs[t] = in[(size_t)b * (C_DIM * HW) + (size_t)t * HW + hw];
        __syncthreads();
        if (t == 0) {
            double s = 0.0;
            for (int c = 0; c < C_DIM; ++c) { double v = (double)xs[c]; s += v * v; }
            x2sh = (float)s;
        }
        __syncthreads();
        const float x2f = x2sh;

        float x0 = xs[lane * 4 + 0], x1 = xs[lane * 4 + 1];
        float x2v = xs[lane * 4 + 2], x3 = xs[lane * 4 + 3];

        float bd = 1e30f; int bk_ = 0x7fffffff;
        for (int k = wid; k < K_CODES; k += 4) {
            float4 ev = *reinterpret_cast<const float4*>(emb + (size_t)k * C_DIM + lane * 4);
            double s = (double)x0 * (double)ev.x + (double)x1 * (double)ev.y
                     + (double)x2v * (double)ev.z + (double)x3 * (double)ev.w;
            #pragma unroll
            for (int off = 32; off > 0; off >>= 1) s += __shfl_down(s, off);
            if (lane == 0) {
                float dotf = (float)s;              // ref's f32 matmul result
                float t1   = x2f + e2[k];           // ref: sum1 + sum2 (f32 add)
                float d    = t1 - 2.0f * dotf;      // ref: T1 - 2*M (f32 sub)
                if (d < bd) { bd = d; bk_ = k; }    // k ascending -> first of min
            }
        }
        if (lane == 0) { bvals[wid] = bd; bks[wid] = bk_; }
        __syncthreads();
        if (t == 0) {
            float v = bvals[0]; int k = bks[0];
            #pragma unroll
            for (int w = 1; w < 4; ++w) {
                if (bvals[w] < v || (bvals[w] == v && bks[w] < k)) { v = bvals[w]; k = bks[w]; }
            }
            kfinal[n] = k;
        }
    }
}

// ---------------- kernel 6: gather, losses, histogram ----------------
__global__ void gather_kernel(const float* __restrict__ in, const float* __restrict__ emb,
                              const int* __restrict__ kfinal,
                              float* __restrict__ out, int* __restrict__ counts,
                              float* __restrict__ sumsq) {
    const int n0 = blockIdx.x * 64;
    const int t = threadIdx.x;
    const int p = t & 63;
    const int n = n0 + p;

    const int idxv = kfinal[n];

    if (blockIdx.y == 0 && t < 64) {
        atomicAdd(&counts[idxv], 1);
        out[IDX_OFF + n] = (float)idxv;
    }

    const int b  = n0 >> 10;
    const int hw = (n0 & 1023) + p;
    const int cbase = blockIdx.y * 128 + (t >> 6) * 32;
    const float* erow = emb + (size_t)idxv * C_DIM;
    float local = 0.f;
    #pragma unroll 4
    for (int i = 0; i < 32; ++i) {
        int c = cbase + i;
        float q = erow[c];
        size_t o = (size_t)b * (C_DIM * HW) + (size_t)c * HW + hw;
        float f = in[o];
        out[o] = q;
        float d = q - f;
        local += d * d;
    }
    #pragma unroll
    for (int off = 32; off > 0; off >>= 1) local += __shfl_down(local, off);
    __shared__ float part[4];
    if ((t & 63) == 0) part[t >> 6] = local;
    __syncthreads();
    if (t == 0) atomicAdd(sumsq, part[0] + part[1] + part[2] + part[3]);
}

// ---------------- kernel 7: scalars ----------------
__global__ void finalize_kernel(const int* __restrict__ counts,
                                const float* __restrict__ sumsq,
                                float* __restrict__ out) {
    const int t = threadIdx.x;
    float h = 0.f;
    for (int i = t; i < K_CODES; i += 256) {
        float pr = (float)counts[i] * (1.0f / (float)N_PTS);
        h += pr * logf(pr + 1e-10f);
    }
    #pragma unroll
    for (int off = 32; off > 0; off >>= 1) h += __shfl_down(h, off);
    __shared__ float hs[4];
    if ((t & 63) == 0) hs[t >> 6] = h;
    __syncthreads();
    if (t == 0) {
        float H = hs[0] + hs[1] + hs[2] + hs[3];
        out[LOSS_OFF] = 1.25f * sumsq[0] / (float)(N_PTS * C_DIM);
        out[PERP_OFF] = expf(-H);
    }
}

extern "C" void kernel_launch(void* const* d_in, const int* in_sizes, int n_in,
                              void* d_out, int out_size, void* d_ws, size_t ws_size,
                              hipStream_t stream) {
    const float* in  = (const float*)d_in[0];   // [16,256,32,32]
    const float* emb = (const float*)d_in[1];   // [8192,256]
    float* out = (float*)d_out;
    char* ws = (char*)d_ws;

    float* e2     = (float*)(ws + WS_E2);
    float* bestv  = (float*)(ws + WS_BESTV);
    float* bestv2 = (float*)(ws + WS_BESTV2);
    int*   bestk  = (int*)  (ws + WS_BESTK);
    int*   kfinal = (int*)  (ws + WS_KFINAL);
    int*   counts = (int*)  (ws + WS_COUNTS);
    float* sumsq  = (float*)(ws + WS_SUMSQ);
    int*   rcount = (int*)  (ws + WS_RCOUNT);
    int*   rlist  = (int*)  (ws + WS_RLIST);
    float* embT   = (float*)(ws + WS_EMBT);

    // zero counts + sumsq + rcount (contiguous)
    hipMemsetAsync(ws + WS_COUNTS, 0, 32768 + 8, stream);

    e2_kernel<<<K_CODES / 4, 256, 0, stream>>>(emb, e2);
    transpose_kernel<<<dim3(K_CODES / 64, C_DIM / 64), 256, 0, stream>>>(emb, embT);
    argmin_kernel<<<dim3(N_PTS / 64, 2), 256, 0, stream>>>(in, embT, e2,
                                                           bestv, bestv2, bestk);
    merge_kernel<<<N_PTS / 256, 256, 0, stream>>>(bestv, bestv2, bestk,
                                                  kfinal, rlist, rcount);
    refine_kernel<<<64, 256, 0, stream>>>(in, emb, e2, rlist, rcount, kfinal);
    gather_kernel<<<dim3(N_PTS / 64, 2), 256, 0, stream>>>(in, emb, kfinal,
                                                           out, counts, sumsq);
    finalize_kernel<<<1, 256, 0, stream>>>(counts, sumsq, out);
}

// Round 8
// 1251.453 us; speedup vs baseline: 1.9035x; 1.9035x over previous
//
#include <hip/hip_runtime.h>

#define N_PTS   16384
#define K_CODES 8192
#define C_DIM   256
#define HW      1024   // 32*32

#define QOUT_SZ  (N_PTS * C_DIM)          // 4194304
#define LOSS_OFF QOUT_SZ
#define PERP_OFF (QOUT_SZ + 1)
#define IDX_OFF  (QOUT_SZ + 2)

// workspace byte offsets
#define WS_E2     0u          // 8192 f32   (32 KB)
#define WS_BESTV  32768u      // 2*16384 f32 (128 KB)
#define WS_BESTV2 163840u     // 2*16384 f32 (128 KB)
#define WS_BESTK  294912u     // 2*16384 i32 (128 KB)
#define WS_KFINAL 425984u     // 16384 i32  (64 KB)
#define WS_COUNTS 491520u     // 8192 i32   (32 KB)
#define WS_SUMSQ  524288u     // 1 f32
#define WS_RCOUNT 524292u     // 1 i32
#define WS_RLIST  524296u     // 16384 i32  (64 KB)
#define WS_EMBT   1048576u    // 256*8192 f32 (8 MB)

// ---------------- kernel 1: ||e_k||^2 (UNCHANGED - passed) ----------------
__global__ void e2_kernel(const float* __restrict__ emb, float* __restrict__ e2) {
    int row  = blockIdx.x * 4 + (threadIdx.x >> 6);
    int lane = threadIdx.x & 63;
    float4 v = *reinterpret_cast<const float4*>(emb + row * C_DIM + lane * 4);
    float s = v.x * v.x + v.y * v.y + v.z * v.z + v.w * v.w;
    #pragma unroll
    for (int off = 32; off > 0; off >>= 1) s += __shfl_down(s, off);
    if (lane == 0) e2[row] = s;
}

// ---------------- kernel 2: embT[c][k] = emb[k][c] (UNCHANGED) ----------------
__global__ void transpose_kernel(const float* __restrict__ emb, float* __restrict__ embT) {
    __shared__ float tile[64][65];
    int k0 = blockIdx.x * 64;
    int c0 = blockIdx.y * 64;
    int cc  = threadIdx.x & 63;
    int kk0 = threadIdx.x >> 6;
    #pragma unroll
    for (int i = 0; i < 16; ++i) {
        int kk = kk0 * 16 + i;
        tile[kk][cc] = emb[(k0 + kk) * C_DIM + c0 + cc];
    }
    __syncthreads();
    int kk  = threadIdx.x & 63;
    int cc0 = threadIdx.x >> 6;
    #pragma unroll
    for (int i = 0; i < 16; ++i) {
        int cc2 = cc0 * 16 + i;
        embT[(c0 + cc2) * K_CODES + k0 + kk] = tile[kk][cc2];
    }
}

// ---------------- kernel 3: f32 argmin, 8x8 thread tile ----------------
// block = 256 threads (8 tp x 32 tk); per block: 64 points x 4096 codes
// per kt: 64p x 256k; per thread: 8p x 8k => 64 FMA per 16 LDS floats
// (2x the FMA/LDS-byte of the 4x4 version -> VALU-bound, not LDS-bound).
// f32 accumulation order over c is IDENTICAL to the passed round (ascending,
// one product at a time) -> bit-identical bestv/bestk.
__global__ __launch_bounds__(256, 2) void argmin_kernel(
    const float* __restrict__ in, const float* __restrict__ embT,
    const float* __restrict__ e2,
    float* __restrict__ bestv_out, float* __restrict__ bestv2_out,
    int* __restrict__ bestk_out) {
    __shared__ float xsT[C_DIM * 64];  // [c][p]  64 KB (reused as reduce scratch)
    __shared__ float es[16 * 256];     // [c16][k256] 16 KB

    const int ntile = blockIdx.x;         // 0..255
    const int khalf = blockIdx.y;         // 0..1
    const int n0 = ntile * 64;
    const int b  = n0 >> 10;
    const int hw0 = n0 & 1023;
    const int t = threadIdx.x;

    // stage x tile: xsT[c][p], coalesced global reads (lane = p)
    {
        int p  = t & 63;
        int c0 = t >> 6;   // 0..3
        const float* src = in + (size_t)b * (C_DIM * HW) + hw0 + p;
        #pragma unroll 4
        for (int i = 0; i < 64; ++i) {
            int c = c0 * 64 + i;
            xsT[c * 64 + p] = src[c * HW];
        }
    }

    const int tp = t & 7;    // 0..7  -> point sub-tile
    const int tk = t >> 3;   // 0..31 -> code sub-tile

    float best[8], best2[8];
    int   bestk[8];
    #pragma unroll
    for (int i = 0; i < 8; ++i) { best[i] = 1e30f; best2[i] = 1e30f; bestk[i] = 0; }

    const int kbase0 = khalf * (K_CODES / 2);
    const int sg = t >> 6, sl = t & 63;   // staging decomposition

    for (int kt = 0; kt < 16; ++kt) {
        const int kbase = kbase0 + kt * 256;
        float acc[8][8] = {};
        for (int cb = 0; cb < 16; ++cb) {
            __syncthreads();   // protects xsT (first iter) and es reuse
            // stage es chunk: 16 c-rows x 256 k (flat, coalesced both sides)
            #pragma unroll
            for (int rr = 0; rr < 4; ++rr) {
                int row = sg * 4 + rr;
                *reinterpret_cast<float4*>(&es[row * 256 + sl * 4]) =
                    *reinterpret_cast<const float4*>(
                        &embT[(size_t)(cb * 16 + row) * K_CODES + kbase + sl * 4]);
            }
            __syncthreads();
            #pragma unroll 4
            for (int c = 0; c < 16; ++c) {
                const float* xb = &xsT[(cb * 16 + c) * 64 + tp * 8];
                const float* eb = &es[c * 256 + tk * 8];
                float4 xa  = *reinterpret_cast<const float4*>(xb);
                float4 xb2 = *reinterpret_cast<const float4*>(xb + 4);
                float4 ea  = *reinterpret_cast<const float4*>(eb);
                float4 eb2 = *reinterpret_cast<const float4*>(eb + 4);
                float xr[8] = {xa.x, xa.y, xa.z, xa.w, xb2.x, xb2.y, xb2.z, xb2.w};
                float er[8] = {ea.x, ea.y, ea.z, ea.w, eb2.x, eb2.y, eb2.z, eb2.w};
                #pragma unroll
                for (int i = 0; i < 8; ++i)
                    #pragma unroll
                    for (int j = 0; j < 8; ++j)
                        acc[i][j] += xr[i] * er[j];
            }
        }
        // epilogue: k ascending within thread -> strict < keeps first occurrence
        #pragma unroll
        for (int j = 0; j < 8; ++j) {
            int k = kbase + tk * 8 + j;
            float ek = e2[k];
            #pragma unroll
            for (int i = 0; i < 8; ++i) {
                float d = ek - 2.0f * acc[i][j];
                if (d < best[i]) { best2[i] = best[i]; best[i] = d; bestk[i] = k; }
                else if (d < best2[i]) { best2[i] = d; }
            }
        }
    }

    // cross-tk reduction via LDS (reuse xsT: 3 arrays of [64][32])
    __syncthreads();
    float* bv  = xsT;
    float* bv2 = xsT + 2048;
    int*   bk  = reinterpret_cast<int*>(xsT + 4096);
    #pragma unroll
    for (int i = 0; i < 8; ++i) {
        int r = (tp * 8 + i) * 32 + tk;
        bv[r] = best[i]; bv2[r] = best2[i]; bk[r] = bestk[i];
    }
    __syncthreads();
    if (t < 64) {
        int base = t * 32;
        float v = bv[base], v2 = bv2[base];
        int   k = bk[base];
        #pragma unroll 8
        for (int j = 1; j < 32; ++j) {
            float nv = bv[base + j], nv2 = bv2[base + j];
            int   nk = bk[base + j];
            if (nv < v || (nv == v && nk < k)) {
                v2 = fminf(v, nv2); v = nv; k = nk;
            } else {
                v2 = fminf(v2, nv);
            }
        }
        bestv_out [khalf * N_PTS + n0 + t] = v;
        bestv2_out[khalf * N_PTS + n0 + t] = v2;
        bestk_out [khalf * N_PTS + n0 + t] = k;
    }
}

// ---------------- kernel 4: merge halves, flag near-ties (UNCHANGED) ----------------
__global__ void merge_kernel(const float* __restrict__ bestv,
                             const float* __restrict__ bestv2,
                             const int* __restrict__ bestk,
                             int* __restrict__ kfinal,
                             int* __restrict__ rlist, int* __restrict__ rcount) {
    int n = blockIdx.x * 256 + threadIdx.x;
    float va = bestv[n],  vb = bestv[N_PTS + n];
    float v2a = bestv2[n], v2b = bestv2[N_PTS + n];
    int   ka = bestk[n],  kb = bestk[N_PTS + n];
    float bst, snd; int k;
    if (vb < va) { bst = vb; k = kb; snd = fminf(va, v2b); }
    else         { bst = va; k = ka; snd = fminf(v2a, vb); }   // tie -> half 0 (smaller k)
    kfinal[n] = k;
    if (snd - bst < 1e-3f) {
        int p = atomicAdd(rcount, 1);
        rlist[p] = n;
    }
}

// ---------------- kernel 5: numpy-f32-EMULATING refine (RESTRUCTURED) ----------------
// Same semantics as the passed round: dot in f64 -> cast f32, then
// d = f32( f32(x2 + e2[k]) - 2*dotf ), first-of-min over ascending k.
// Structure changed from wave-per-k shuffle chains (latency-bound, 1211us)
// to thread-per-k with register f64 accumulators (4 independent chains).
__global__ void refine_kernel(const float* __restrict__ in, const float* __restrict__ emb,
                              const float* __restrict__ e2,
                              const int* __restrict__ rlist, const int* __restrict__ rcount,
                              int* __restrict__ kfinal) {
    __shared__ float xs[C_DIM];
    __shared__ float x2sh;
    __shared__ float rv[256];
    __shared__ int   rk[256];
    const int t = threadIdx.x;
    const int njobs = *rcount;

    for (int job = blockIdx.x; job < njobs; job += gridDim.x) {
        const int n = rlist[job];
        const int b = n >> 10, hw = n & 1023;
        __syncthreads();   // protect xs/x2sh/rv reuse across jobs
        xs[t] = in[(size_t)b * (C_DIM * HW) + (size_t)t * HW + hw];
        __syncthreads();
        if (t == 0) {
            double s = 0.0;
            for (int c = 0; c < C_DIM; ++c) { double v = (double)xs[c]; s += v * v; }
            x2sh = (float)s;
        }
        __syncthreads();
        const float x2f = x2sh;

        float bd = 1e30f; int bk_ = 0x7fffffff;
        for (int k = t; k < K_CODES; k += 256) {
            const float4* er = reinterpret_cast<const float4*>(emb + (size_t)k * C_DIM);
            double s0 = 0.0, s1 = 0.0, s2 = 0.0, s3 = 0.0;
            #pragma unroll 8
            for (int c4 = 0; c4 < C_DIM / 4; ++c4) {
                float4 ev = er[c4];
                float4 xv = *reinterpret_cast<const float4*>(&xs[c4 * 4]);
                s0 += (double)xv.x * (double)ev.x;
                s1 += (double)xv.y * (double)ev.y;
                s2 += (double)xv.z * (double)ev.z;
                s3 += (double)xv.w * (double)ev.w;
            }
            double s = (s0 + s1) + (s2 + s3);
            float dotf = (float)s;              // ref's f32 matmul result
            float t1   = x2f + e2[k];           // ref: sum1 + sum2 (f32 add)
            float d    = t1 - 2.0f * dotf;      // ref: T1 - 2*M (f32 sub)
            if (d < bd) { bd = d; bk_ = k; }    // k ascending within thread
        }
        rv[t] = bd; rk[t] = bk_;
        __syncthreads();
        if (t == 0) {
            float v = rv[0]; int k = rk[0];
            for (int j = 1; j < 256; ++j) {
                if (rv[j] < v || (rv[j] == v && rk[j] < k)) { v = rv[j]; k = rk[j]; }
            }
            kfinal[n] = k;
        }
    }
}

// ---------------- kernel 6: gather, losses, histogram (UNCHANGED) ----------------
__global__ void gather_kernel(const float* __restrict__ in, const float* __restrict__ emb,
                              const int* __restrict__ kfinal,
                              float* __restrict__ out, int* __restrict__ counts,
                              float* __restrict__ sumsq) {
    const int n0 = blockIdx.x * 64;
    const int t = threadIdx.x;
    const int p = t & 63;
    const int n = n0 + p;

    const int idxv = kfinal[n];

    if (blockIdx.y == 0 && t < 64) {
        atomicAdd(&counts[idxv], 1);
        out[IDX_OFF + n] = (float)idxv;
    }

    const int b  = n0 >> 10;
    const int hw = (n0 & 1023) + p;
    const int cbase = blockIdx.y * 128 + (t >> 6) * 32;
    const float* erow = emb + (size_t)idxv * C_DIM;
    float local = 0.f;
    #pragma unroll 4
    for (int i = 0; i < 32; ++i) {
        int c = cbase + i;
        float q = erow[c];
        size_t o = (size_t)b * (C_DIM * HW) + (size_t)c * HW + hw;
        float f = in[o];
        out[o] = q;
        float d = q - f;
        local += d * d;
    }
    #pragma unroll
    for (int off = 32; off > 0; off >>= 1) local += __shfl_down(local, off);
    __shared__ float part[4];
    if ((t & 63) == 0) part[t >> 6] = local;
    __syncthreads();
    if (t == 0) atomicAdd(sumsq, part[0] + part[1] + part[2] + part[3]);
}

// ---------------- kernel 7: scalars (UNCHANGED) ----------------
__global__ void finalize_kernel(const int* __restrict__ counts,
                                const float* __restrict__ sumsq,
                                float* __restrict__ out) {
    const int t = threadIdx.x;
    float h = 0.f;
    for (int i = t; i < K_CODES; i += 256) {
        float pr = (float)counts[i] * (1.0f / (float)N_PTS);
        h += pr * logf(pr + 1e-10f);
    }
    #pragma unroll
    for (int off = 32; off > 0; off >>= 1) h += __shfl_down(h, off);
    __shared__ float hs[4];
    if ((t & 63) == 0) hs[t >> 6] = h;
    __syncthreads();
    if (t == 0) {
        float H = hs[0] + hs[1] + hs[2] + hs[3];
        out[LOSS_OFF] = 1.25f * sumsq[0] / (float)(N_PTS * C_DIM);
        out[PERP_OFF] = expf(-H);
    }
}

extern "C" void kernel_launch(void* const* d_in, const int* in_sizes, int n_in,
                              void* d_out, int out_size, void* d_ws, size_t ws_size,
                              hipStream_t stream) {
    const float* in  = (const float*)d_in[0];   // [16,256,32,32]
    const float* emb = (const float*)d_in[1];   // [8192,256]
    float* out = (float*)d_out;
    char* ws = (char*)d_ws;

    float* e2     = (float*)(ws + WS_E2);
    float* bestv  = (float*)(ws + WS_BESTV);
    float* bestv2 = (float*)(ws + WS_BESTV2);
    int*   bestk  = (int*)  (ws + WS_BESTK);
    int*   kfinal = (int*)  (ws + WS_KFINAL);
    int*   counts = (int*)  (ws + WS_COUNTS);
    float* sumsq  = (float*)(ws + WS_SUMSQ);
    int*   rcount = (int*)  (ws + WS_RCOUNT);
    int*   rlist  = (int*)  (ws + WS_RLIST);
    float* embT   = (float*)(ws + WS_EMBT);

    // zero counts + sumsq + rcount (contiguous)
    hipMemsetAsync(ws + WS_COUNTS, 0, 32768 + 8, stream);

    e2_kernel<<<K_CODES / 4, 256, 0, stream>>>(emb, e2);
    transpose_kernel<<<dim3(K_CODES / 64, C_DIM / 64), 256, 0, stream>>>(emb, embT);
    argmin_kernel<<<dim3(N_PTS / 64, 2), 256, 0, stream>>>(in, embT, e2,
                                                           bestv, bestv2, bestk);
    merge_kernel<<<N_PTS / 256, 256, 0, stream>>>(bestv, bestv2, bestk,
                                                  kfinal, rlist, rcount);
    refine_kernel<<<128, 256, 0, stream>>>(in, emb, e2, rlist, rcount, kfinal);
    gather_kernel<<<dim3(N_PTS / 64, 2), 256, 0, stream>>>(in, emb, kfinal,
                                                           out, counts, sumsq);
    finalize_kernel<<<1, 256, 0, stream>>>(counts, sumsq, out);
}